// Round 15
// baseline (138.235 us; speedup 1.0000x reference)
//
#include <hip/hip_runtime.h>

#define N_NODES 100000
#define N_EDGES 1200000
#define D_IN 256
#define D_OUT 64

#define BUCKET_BITS 5
#define BUCKET_ROWS 32
#define N_BUCKETS   (N_NODES / BUCKET_ROWS)      // 3125 exact
#define NBLK_E      640
#define EPB         (N_EDGES / NBLK_E)           // 1875 exact
#define N_GROUPS    196                           // ceil(3125/16)
#define CPL         10                            // chunks per lane (640/64)
#define CAP         1536                          // LDS edge staging per bucket

// c2d[group][chunk][16] : one 64B line per (group,chunk). 196*640*16*4 = 8,028,160 B.
#define C2D_IDX(b, k) ((((size_t)((b) >> 4) * NBLK_E + (k)) << 4) | ((b) & 15))

// ---- workspace layout (bytes) ----------------------------------------------
#define OFF_SUPPORT   0u            // bf16 support: 12,800,000
#define OFF_BSUM      12800000u     // 3136*4 = 12,544
#define OFF_BBASE     12812544u     // 12,544
#define OFF_ETMP      12825088u     // 1.2M*8 = 9,600,000
#define OFF_EDGEG     22425088u     // 9,600,000 (c2d alias: 8,028,160)
#define OFF_C2D       OFF_EDGEG
#define WS_NEEDED     32025088u

using bf16x8 = __attribute__((ext_vector_type(8))) short;
using f32x4  = __attribute__((ext_vector_type(4))) float;

static __device__ __forceinline__ ushort f32_to_bf16_rne(float f) {
    unsigned bits = __float_as_uint(f);
    unsigned r = (bits + 0x7FFFu + ((bits >> 16) & 1u)) >> 16;
    return (ushort)r;
}
static __device__ __forceinline__ float bf16_to_f32(ushort u) {
    return __uint_as_float((unsigned)u << 16);
}
static __device__ __forceinline__ unsigned pack2bf(float a, float b) {
    return (unsigned)f32_to_bf16_rne(a) | ((unsigned)f32_to_bf16_rne(b) << 16);
}

// ---------------------------------------------------------------------------
// support(bf16) = X @ W — BARRIER-FREE direct-A MFMA gemm.
// A-fragments load straight from global X (each X element read exactly once;
// lane l: 32 contiguous bytes of row row0+w*32+(l&15) at k-offset (l>>4)*8 —
// the m89-verified A layout), converted to bf16 in registers. W staged once
// in LDS, conflict-free (lane<->column, ds_write_b128, 8 lanes/bank-quad =
// 8-sweep minimum). ZERO barriers in the k-loop.
// ---------------------------------------------------------------------------
__global__ __launch_bounds__(256) void gemm_xw_mfma(const float* __restrict__ X,
                                                    const float* __restrict__ W,
                                                    ushort* __restrict__ support) {
    __shared__ ushort WtT[32][64][8];   // WtT[kg][c][e] = W[kg*8+e][c]; 32 KB

    const int t = threadIdx.x;
    const int lane = t & 63;
    const int w = t >> 6;
    const int lr = lane & 15;
    const int lg = lane >> 4;
    const int row0 = blockIdx.x * 128;

    // ---- stage W once, conflict-free ----
    {
        const int c   = t & 63;     // column = lane -> coalesced global reads
        const int kg0 = t >> 6;     // 0..3
#pragma unroll
        for (int i = 0; i < 8; ++i) {
            int kg = kg0 + i * 4;   // 0..31
            uint4 u;
            u.x = pack2bf(W[(size_t)(kg * 8 + 0) * D_OUT + c],
                          W[(size_t)(kg * 8 + 1) * D_OUT + c]);
            u.y = pack2bf(W[(size_t)(kg * 8 + 2) * D_OUT + c],
                          W[(size_t)(kg * 8 + 3) * D_OUT + c]);
            u.z = pack2bf(W[(size_t)(kg * 8 + 4) * D_OUT + c],
                          W[(size_t)(kg * 8 + 5) * D_OUT + c]);
            u.w = pack2bf(W[(size_t)(kg * 8 + 6) * D_OUT + c],
                          W[(size_t)(kg * 8 + 7) * D_OUT + c]);
            *reinterpret_cast<uint4*>(&WtT[kg][c][0]) = u;
        }
    }
    __syncthreads();

    const int ra0 = row0 + w * 32 + lr;
    const int ra1 = ra0 + 16;
    const bool v0 = ra0 < N_NODES;
    const bool v1 = ra1 < N_NODES;
    const float* pa0 = X + (size_t)ra0 * D_IN + lg * 8;
    const float* pa1 = X + (size_t)ra1 * D_IN + lg * 8;

    f32x4 acc[2][4];
#pragma unroll
    for (int mi = 0; mi < 2; ++mi)
#pragma unroll
        for (int ni = 0; ni < 4; ++ni) acc[mi][ni] = (f32x4){0.f, 0.f, 0.f, 0.f};

    const float4 z4 = make_float4(0.f, 0.f, 0.f, 0.f);

#pragma unroll
    for (int kt = 0; kt < 8; ++kt) {
        float4 x00 = v0 ? *reinterpret_cast<const float4*>(pa0 + kt * 32)     : z4;
        float4 x01 = v0 ? *reinterpret_cast<const float4*>(pa0 + kt * 32 + 4) : z4;
        float4 x10 = v1 ? *reinterpret_cast<const float4*>(pa1 + kt * 32)     : z4;
        float4 x11 = v1 ? *reinterpret_cast<const float4*>(pa1 + kt * 32 + 4) : z4;

        uint4 ua, ub;
        ua.x = pack2bf(x00.x, x00.y); ua.y = pack2bf(x00.z, x00.w);
        ua.z = pack2bf(x01.x, x01.y); ua.w = pack2bf(x01.z, x01.w);
        ub.x = pack2bf(x10.x, x10.y); ub.y = pack2bf(x10.z, x10.w);
        ub.z = pack2bf(x11.x, x11.y); ub.w = pack2bf(x11.z, x11.w);
        bf16x8 a0 = *reinterpret_cast<bf16x8*>(&ua);
        bf16x8 a1 = *reinterpret_cast<bf16x8*>(&ub);

#pragma unroll
        for (int ni = 0; ni < 4; ++ni) {
            bf16x8 b = *reinterpret_cast<const bf16x8*>(&WtT[kt * 4 + lg][ni * 16 + lr][0]);
            acc[0][ni] = __builtin_amdgcn_mfma_f32_16x16x32_bf16(a0, b, acc[0][ni], 0, 0, 0);
            acc[1][ni] = __builtin_amdgcn_mfma_f32_16x16x32_bf16(a1, b, acc[1][ni], 0, 0, 0);
        }
    }

    // ---- C write: D row = lg*4+reg, col = lr (m89-verified) ----
#pragma unroll
    for (int mi = 0; mi < 2; ++mi) {
#pragma unroll
        for (int reg = 0; reg < 4; ++reg) {
            int grow = row0 + w * 32 + mi * 16 + lg * 4 + reg;
            if (grow < N_NODES) {
#pragma unroll
                for (int ni = 0; ni < 4; ++ni)
                    support[(size_t)grow * D_OUT + ni * 16 + lr] =
                        f32_to_bf16_rne(acc[mi][ni][reg]);
            }
        }
    }
}

// ---------------------------------------------------------------------------
// Per-chunk bucket histogram (LDS-private) -> line-granular c2d.
// ---------------------------------------------------------------------------
__global__ __launch_bounds__(256) void bucket_count(const int* __restrict__ rows,
                                                    int* __restrict__ c2d) {
    __shared__ int h[N_BUCKETS];
    for (int i = threadIdx.x; i < N_BUCKETS; i += 256) h[i] = 0;
    __syncthreads();
    const int base = blockIdx.x * EPB;
    for (int i = threadIdx.x; i < EPB; i += 256)
        atomicAdd(&h[rows[base + i] >> BUCKET_BITS], 1);
    __syncthreads();
    const int k = blockIdx.x;
    for (int b = threadIdx.x; b < N_GROUPS * 16; b += 256)
        c2d[C2D_IDX(b, k)] = (b < N_BUCKETS) ? h[b] : 0;
}

// ---------------------------------------------------------------------------
// Per-bucket exclusive scan over 640 chunk counts (grouped/coalesced layout);
// emits per-bucket totals bsum[b]. (Validated R10-R13.)
// ---------------------------------------------------------------------------
__global__ __launch_bounds__(256) void scan_groups(int* __restrict__ c2d,
                                                   int* __restrict__ bsum) {
    __shared__ int T[16][NBLK_E + 4];
    const int t = threadIdx.x;
    const int w = t >> 6;
    const int l = t & 63;
    const size_t base = (size_t)blockIdx.x * NBLK_E * 16;

    for (int i = t; i < NBLK_E * 16; i += 256) {
        int k = i >> 4, bl = i & 15;
        T[bl][k] = c2d[base + i];
    }
    __syncthreads();

#pragma unroll
    for (int q = 0; q < 4; ++q) {
        const int bl = w * 4 + q;
        int loc[CPL];
        int sum = 0;
#pragma unroll
        for (int j = 0; j < CPL; ++j) {
            int v = T[bl][l * CPL + j];
            loc[j] = sum;
            sum += v;
        }
        int s = sum;
#pragma unroll
        for (int off = 1; off < 64; off <<= 1) {
            int u = __shfl_up(s, off);
            if (l >= off) s += u;
        }
        if (l == 63) bsum[blockIdx.x * 16 + bl] = s;   // bucket total
        int ex = s - sum;
#pragma unroll
        for (int j = 0; j < CPL; ++j)
            T[bl][l * CPL + j] = ex + loc[j];
    }
    __syncthreads();

    for (int i = t; i < NBLK_E * 16; i += 256) {
        int k = i >> 4, bl = i & 15;
        c2d[base + i] = T[bl][k];
    }
}

// ---------------------------------------------------------------------------
// Scatter: per-block replicated bucket-base scan (kills scan_buckets
// dispatch; validated R13). Block 0 persists bbase for sort_gather.
// Record: x = col(17b) | (row&31)<<17 ; y = val bits.
// ---------------------------------------------------------------------------
__global__ __launch_bounds__(256) void bucket_scatter3(const int* __restrict__ rows,
                                                       const int* __restrict__ cols,
                                                       const float* __restrict__ vals,
                                                       const int* __restrict__ c2d,
                                                       const int* __restrict__ bsum,
                                                       int* __restrict__ bbase,
                                                       uint2* __restrict__ etmp) {
    __shared__ int s[256];
    __shared__ int off[N_BUCKETS];
    const int t = threadIdx.x;
    const int blk = blockIdx.x;

    int loc[13];
    int sum = 0;
#pragma unroll
    for (int j = 0; j < 13; ++j) {
        int idx = t * 13 + j;
        int v = (idx < N_BUCKETS) ? bsum[idx] : 0;
        loc[j] = sum;
        sum += v;
    }
    s[t] = sum;
    __syncthreads();
#pragma unroll
    for (int o = 1; o < 256; o <<= 1) {
        int x = (t >= o) ? s[t - o] : 0;
        __syncthreads();
        s[t] += x;
        __syncthreads();
    }
    int base0 = s[t] - sum;
#pragma unroll
    for (int j = 0; j < 13; ++j) {
        int idx = t * 13 + j;
        if (idx < N_BUCKETS) {
            int bb = base0 + loc[j];
            off[idx] = bb + c2d[C2D_IDX(idx, blk)];
            if (blk == 0) bbase[idx] = bb;
        }
    }
    __syncthreads();

    const int base = blk * EPB;
    for (int i = t; i < EPB; i += 256) {
        int e = base + i;
        int r = rows[e];
        int b = r >> BUCKET_BITS;
        int pos = atomicAdd(&off[b], 1);
        etmp[pos] = make_uint2((unsigned)cols[e] |
                               ((unsigned)(r & (BUCKET_ROWS - 1)) << 17),
                               __float_as_uint(vals[e]));
    }
}

// ---------------------------------------------------------------------------
// Fused sort+gather (unchanged, validated R11-R13): one block per bucket.
// ---------------------------------------------------------------------------
__global__ __launch_bounds__(256) void sort_gather(const uint2* __restrict__ etmp,
                                                   const int* __restrict__ bbase,
                                                   const int* __restrict__ bsum,
                                                   const ushort* __restrict__ support,
                                                   uint2* __restrict__ edge_g,
                                                   float* __restrict__ out) {
    __shared__ uint2 eL[CAP];                // 12,288 B
    __shared__ int cnt[BUCKET_ROWS], pos[BUCKET_ROWS], fill[BUCKET_ROWS];
    const int t = threadIdx.x;
    const int lane = t & 63;
    const int w = t >> 6;
    const int b = blockIdx.x;
    const int r0 = b << BUCKET_BITS;
    const int s0 = bbase[b];
    const int n  = bsum[b];

    if (t < BUCKET_ROWS) cnt[t] = 0;
    __syncthreads();

    for (int i = t; i < n; i += 256)
        atomicAdd(&cnt[etmp[s0 + i].x >> 17], 1);
    __syncthreads();

    if (t < 64) {
        int v = (t < 32) ? cnt[t] : 0;
        int s = v;
#pragma unroll
        for (int off = 1; off < 32; off <<= 1) {
            int u = __shfl_up(s, off);
            if (lane >= off) s += u;
        }
        if (t < 32) { pos[t] = s - v; fill[t] = 0; }
    }
    __syncthreads();

    const bool inLDS = (n <= CAP);
    if (inLDS) {
        for (int i = t; i < n; i += 256) {
            uint2 u = etmp[s0 + i];
            int r = (int)(u.x >> 17);
            int p = pos[r] + atomicAdd(&fill[r], 1);
            eL[p] = make_uint2(u.x & 0x1FFFFu, u.y);
        }
    } else {
        for (int i = t; i < n; i += 256) {
            uint2 u = etmp[s0 + i];
            int r = (int)(u.x >> 17);
            int p = pos[r] + atomicAdd(&fill[r], 1);
            edge_g[s0 + p] = make_uint2(u.x & 0x1FFFFu, u.y);
        }
    }
    __syncthreads();

    const int h = lane >> 5;
    const int c = lane & 31;

#define GATHER_BODY(SRC)                                                          \
    for (int rr = w; rr < BUCKET_ROWS; rr += 4) {                                 \
        int e = pos[rr], end = pos[rr] + cnt[rr];                                 \
        float2 acc = {0.f, 0.f};                                                  \
        for (; e + 3 < end; e += 4) {                                             \
            uint2 p0 = SRC(e + h);                                                \
            uint2 p1 = SRC(e + 2 + h);                                            \
            unsigned s0v = *reinterpret_cast<const unsigned*>(                    \
                support + (size_t)p0.x * D_OUT + 2 * c);                          \
            unsigned s1v = *reinterpret_cast<const unsigned*>(                    \
                support + (size_t)p1.x * D_OUT + 2 * c);                          \
            float v0 = __uint_as_float(p0.y);                                     \
            float v1 = __uint_as_float(p1.y);                                     \
            acc.x = fmaf(v0, bf16_to_f32((ushort)(s0v & 0xFFFFu)), acc.x);        \
            acc.y = fmaf(v0, bf16_to_f32((ushort)(s0v >> 16)), acc.y);            \
            acc.x = fmaf(v1, bf16_to_f32((ushort)(s1v & 0xFFFFu)), acc.x);        \
            acc.y = fmaf(v1, bf16_to_f32((ushort)(s1v >> 16)), acc.y);            \
        }                                                                         \
        for (int ee = e + h; ee < end; ee += 2) {                                 \
            uint2 p = SRC(ee);                                                    \
            unsigned sv = *reinterpret_cast<const unsigned*>(                     \
                support + (size_t)p.x * D_OUT + 2 * c);                           \
            float v = __uint_as_float(p.y);                                       \
            acc.x = fmaf(v, bf16_to_f32((ushort)(sv & 0xFFFFu)), acc.x);          \
            acc.y = fmaf(v, bf16_to_f32((ushort)(sv >> 16)), acc.y);              \
        }                                                                         \
        acc.x += __shfl_xor(acc.x, 32);                                           \
        acc.y += __shfl_xor(acc.y, 32);                                           \
        if (h == 0)                                                               \
            *reinterpret_cast<float2*>(out + (size_t)(r0 + rr) * D_OUT + 2 * c) = acc; \
    }

    if (inLDS) {
#define SRCL(i) eL[i]
        GATHER_BODY(SRCL)
#undef SRCL
    } else {
        const uint2* eg = edge_g + s0;
#define SRCG(i) eg[i]
        GATHER_BODY(SRCG)
#undef SRCG
    }
#undef GATHER_BODY
}

// ---------------------------------------------------------------------------
// Fallback path (ws too small): zero + atomic scatter from bf16 support.
// ---------------------------------------------------------------------------
__global__ void zero_out(float4* __restrict__ out, int n4) {
    int i = blockIdx.x * blockDim.x + threadIdx.x;
    int stride = gridDim.x * blockDim.x;
    for (; i < n4; i += stride) out[i] = float4{0.0f, 0.0f, 0.0f, 0.0f};
}

__global__ __launch_bounds__(256) void spmm_scatter(const int* __restrict__ rows,
                                                    const int* __restrict__ cols,
                                                    const float* __restrict__ vals,
                                                    const ushort* __restrict__ support,
                                                    float* __restrict__ out,
                                                    int n_edges) {
    const int lane = threadIdx.x & 63;
    const int wave_global = (int)((blockIdx.x * blockDim.x + threadIdx.x) >> 6);
    const int n_waves = (int)((gridDim.x * blockDim.x) >> 6);

    for (int base = wave_global * 64; base < n_edges; base += n_waves * 64) {
        int my_e = base + lane;
        int r = rows[my_e];
        int c = cols[my_e];
        float v = vals[my_e];

        int cnt = min(64, n_edges - base);
        for (int i = 0; i < cnt; ++i) {
            int row = __shfl(r, i);
            int col = __shfl(c, i);
            float val = __shfl(v, i);
            float s = bf16_to_f32(support[(size_t)col * D_OUT + lane]);
            atomicAdd(&out[(size_t)row * D_OUT + lane], val * s);
        }
    }
}

extern "C" void kernel_launch(void* const* d_in, const int* in_sizes, int n_in,
                              void* d_out, int out_size, void* d_ws, size_t ws_size,
                              hipStream_t stream) {
    const float* X      = (const float*)d_in[0];
    const float* W      = (const float*)d_in[1];
    const int*   A_rows = (const int*)d_in[2];
    const int*   A_cols = (const int*)d_in[3];
    const float* A_vals = (const float*)d_in[4];
    float* out = (float*)d_out;

    char* ws = (char*)d_ws;
    ushort* support = (ushort*)(ws + OFF_SUPPORT);

    const int gemm_blocks = (N_NODES + 127) / 128;  // 782

    if (ws_size >= (size_t)WS_NEEDED) {
        int*   bsum   = (int*)(ws + OFF_BSUM);
        int*   bbase  = (int*)(ws + OFF_BBASE);
        int*   c2d    = (int*)(ws + OFF_C2D);     // aliases edge_g region
        uint2* etmp   = (uint2*)(ws + OFF_ETMP);
        uint2* edge_g = (uint2*)(ws + OFF_EDGEG);

        // d1: per-chunk bucket histograms
        bucket_count<<<NBLK_E, 256, 0, stream>>>(A_rows, c2d);
        // d2: per-bucket chunk-offset scan + bucket totals
        scan_groups<<<N_GROUPS, 256, 0, stream>>>(c2d, bsum);
        // d3: scatter (bucket bases computed in-block; block 0 persists bbase)
        bucket_scatter3<<<NBLK_E, 256, 0, stream>>>(A_rows, A_cols, A_vals,
                                                    c2d, bsum, bbase, etmp);
        // d4: support = bf16(X @ W)  (barrier-free direct-A MFMA)
        gemm_xw_mfma<<<gemm_blocks, 256, 0, stream>>>(X, W, support);
        // d5: fused per-bucket row-sort + gather
        sort_gather<<<N_BUCKETS, 256, 0, stream>>>(etmp, bbase, bsum,
                                                   support, edge_g, out);
    } else {
        int n4 = (N_NODES * D_OUT) / 4;
        zero_out<<<2048, 256, 0, stream>>>((float4*)out, n4);
        gemm_xw_mfma<<<gemm_blocks, 256, 0, stream>>>(X, W, support);
        int chunks = N_EDGES / 64;
        spmm_scatter<<<(chunks + 3) / 4, 256, 0, stream>>>(A_rows, A_cols, A_vals,
                                                           support, out, N_EDGES);
    }
}

// Round 16
// 111.376 us; speedup vs baseline: 1.2412x; 1.2412x over previous
//
#include <hip/hip_runtime.h>

#define N_NODES 100000
#define N_EDGES 1200000
#define D_IN 256
#define D_OUT 64

#define BUCKET_BITS 5
#define BUCKET_ROWS 32
#define N_BUCKETS   (N_NODES / BUCKET_ROWS)      // 3125 exact
#define NBLK_E      640
#define EPB         (N_EDGES / NBLK_E)           // 1875 exact
#define N_GROUPS    196                           // ceil(3125/16)
#define CPL         10                            // chunks per lane (640/64)
#define CAP         1536                          // LDS edge staging per bucket

// c2d[group][chunk][16] : one 64B line per (group,chunk). 196*640*16*4 = 8,028,160 B.
#define C2D_IDX(b, k) ((((size_t)((b) >> 4) * NBLK_E + (k)) << 4) | ((b) & 15))

// ---- workspace layout (bytes) ----------------------------------------------
#define OFF_SUPPORT   0u            // bf16 support: 12,800,000
#define OFF_BSUM      12800000u     // 12,544
#define OFF_BBASE     12812544u     // 12,544
#define OFF_WBF       12825088u     // 32,768 (bf16 W, [kg][c][8] layout)
#define OFF_ETMP      12857856u     // 1.2M*8 = 9,600,000
#define OFF_EDGEG     22457856u     // 9,600,000 (c2d alias: 8,028,160)
#define OFF_C2D       OFF_EDGEG
#define WS_NEEDED     32057856u

using bf16x8 = __attribute__((ext_vector_type(8))) short;
using f32x4  = __attribute__((ext_vector_type(4))) float;

static __device__ __forceinline__ ushort f32_to_bf16_rne(float f) {
    unsigned bits = __float_as_uint(f);
    unsigned r = (bits + 0x7FFFu + ((bits >> 16) & 1u)) >> 16;
    return (ushort)r;
}
static __device__ __forceinline__ float bf16_to_f32(ushort u) {
    return __uint_as_float((unsigned)u << 16);
}
static __device__ __forceinline__ unsigned pack2bf(float a, float b) {
    return (unsigned)f32_to_bf16_rne(a) | ((unsigned)f32_to_bf16_rne(b) << 16);
}

// W-prep body: block kb (0..7) converts kg = kb*4 + (t>>6) into Wbf[kg][c][8].
static __device__ __forceinline__ void wprep_body(int kb, int t,
                                                  const float* __restrict__ W,
                                                  ushort* __restrict__ Wbf) {
    const int c  = t & 63;
    const int kg = kb * 4 + (t >> 6);
    uint4 u;
    u.x = pack2bf(W[(size_t)(kg * 8 + 0) * D_OUT + c], W[(size_t)(kg * 8 + 1) * D_OUT + c]);
    u.y = pack2bf(W[(size_t)(kg * 8 + 2) * D_OUT + c], W[(size_t)(kg * 8 + 3) * D_OUT + c]);
    u.z = pack2bf(W[(size_t)(kg * 8 + 4) * D_OUT + c], W[(size_t)(kg * 8 + 5) * D_OUT + c]);
    u.w = pack2bf(W[(size_t)(kg * 8 + 6) * D_OUT + c], W[(size_t)(kg * 8 + 7) * D_OUT + c]);
    *reinterpret_cast<uint4*>(Wbf + ((size_t)kg * 64 + c) * 8) = u;
}

// ---------------------------------------------------------------------------
// support(bf16) = X @ W — MFMA 16x16x32 bf16.
// X: coalesced LDS staging (R4-proven pattern), DOUBLE-BUFFERED -> one
// barrier per k-step. W: read directly from global bf16 Wbf (L2-resident,
// 16B/lane fully-used lines) -> no W LDS, LDS = 16 KB -> ~6 blocks/CU.
// ---------------------------------------------------------------------------
__global__ __launch_bounds__(256) void gemm_xw_mfma(const float* __restrict__ X,
                                                    const ushort* __restrict__ Wbf,
                                                    ushort* __restrict__ support) {
    __shared__ ushort Xs[2][4][128][8];   // 16 KB (2 buffers)

    const int t = threadIdx.x;
    const int lane = t & 63;
    const int w = t >> 6;
    const int lr = lane & 15;
    const int lg = lane >> 4;
    const int row0 = blockIdx.x * 128;

    int  xrow[4], xq[4];
    bool xval[4];
#pragma unroll
    for (int p = 0; p < 4; ++p) {
        int idx = t + p * 256;
        xrow[p] = idx >> 3;
        xq[p]   = idx & 7;
        xval[p] = (row0 + xrow[p]) < N_NODES;
    }

    float4 xreg[4];
#pragma unroll
    for (int p = 0; p < 4; ++p) {
        xreg[p] = make_float4(0.f, 0.f, 0.f, 0.f);
        if (xval[p])
            xreg[p] = *reinterpret_cast<const float4*>(
                X + (size_t)(row0 + xrow[p]) * D_IN + xq[p] * 4);
    }

#define STAGE_X(buf)                                                              \
    {                                                                             \
        _Pragma("unroll")                                                         \
        for (int p = 0; p < 4; ++p) {                                             \
            uint2 u;                                                              \
            u.x = pack2bf(xreg[p].x, xreg[p].y);                                  \
            u.y = pack2bf(xreg[p].z, xreg[p].w);                                  \
            *reinterpret_cast<uint2*>(&Xs[buf][xq[p] >> 1][xrow[p]][(xq[p] & 1) * 4]) = u; \
        }                                                                         \
    }

    STAGE_X(0)
    __syncthreads();

    f32x4 acc[2][4];
#pragma unroll
    for (int mi = 0; mi < 2; ++mi)
#pragma unroll
        for (int ni = 0; ni < 4; ++ni) acc[mi][ni] = (f32x4){0.f, 0.f, 0.f, 0.f};

#pragma unroll
    for (int kt = 0; kt < 8; ++kt) {
        const int cur = kt & 1;

        // prefetch next X k-slab early (vmcnt waits land after the MFMAs)
        if (kt < 7) {
#pragma unroll
            for (int p = 0; p < 4; ++p) {
                if (xval[p])
                    xreg[p] = *reinterpret_cast<const float4*>(
                        X + (size_t)(row0 + xrow[p]) * D_IN + (kt + 1) * 32 + xq[p] * 4);
            }
        }

        bf16x8 a0 = *reinterpret_cast<const bf16x8*>(&Xs[cur][lg][w * 32 + lr][0]);
        bf16x8 a1 = *reinterpret_cast<const bf16x8*>(&Xs[cur][lg][w * 32 + 16 + lr][0]);
        const ushort* wb = Wbf + ((size_t)(kt * 4 + lg) * 64) * 8;
#pragma unroll
        for (int ni = 0; ni < 4; ++ni) {
            bf16x8 b = *reinterpret_cast<const bf16x8*>(wb + (size_t)(ni * 16 + lr) * 8);
            acc[0][ni] = __builtin_amdgcn_mfma_f32_16x16x32_bf16(a0, b, acc[0][ni], 0, 0, 0);
            acc[1][ni] = __builtin_amdgcn_mfma_f32_16x16x32_bf16(a1, b, acc[1][ni], 0, 0, 0);
        }

        if (kt < 7) STAGE_X(cur ^ 1)
        __syncthreads();
    }
#undef STAGE_X

    // ---- C write: D row = lg*4+reg, col = lr (m89-verified) ----
#pragma unroll
    for (int mi = 0; mi < 2; ++mi) {
#pragma unroll
        for (int reg = 0; reg < 4; ++reg) {
            int grow = row0 + w * 32 + mi * 16 + lg * 4 + reg;
            if (grow < N_NODES) {
#pragma unroll
                for (int ni = 0; ni < 4; ++ni)
                    support[(size_t)grow * D_OUT + ni * 16 + lr] =
                        f32_to_bf16_rne(acc[mi][ni][reg]);
            }
        }
    }
}

// ---------------------------------------------------------------------------
// d1: per-chunk bucket histogram (blocks 0..639) + W-prep roles (blocks 640..647).
// ---------------------------------------------------------------------------
__global__ __launch_bounds__(256) void bucket_count(const int* __restrict__ rows,
                                                    int* __restrict__ c2d,
                                                    const float* __restrict__ W,
                                                    ushort* __restrict__ Wbf) {
    __shared__ int h[N_BUCKETS];
    const int bid = blockIdx.x;
    if (bid >= NBLK_E) {
        wprep_body(bid - NBLK_E, threadIdx.x, W, Wbf);
        return;
    }
    for (int i = threadIdx.x; i < N_BUCKETS; i += 256) h[i] = 0;
    __syncthreads();
    const int base = bid * EPB;
    for (int i = threadIdx.x; i < EPB; i += 256)
        atomicAdd(&h[rows[base + i] >> BUCKET_BITS], 1);
    __syncthreads();
    for (int b = threadIdx.x; b < N_GROUPS * 16; b += 256)
        c2d[C2D_IDX(b, bid)] = (b < N_BUCKETS) ? h[b] : 0;
}

// ---------------------------------------------------------------------------
// Per-bucket exclusive scan over 640 chunk counts (grouped/coalesced layout);
// emits per-bucket totals bsum[b]. (Validated R10-R14.)
// ---------------------------------------------------------------------------
__global__ __launch_bounds__(256) void scan_groups(int* __restrict__ c2d,
                                                   int* __restrict__ bsum) {
    __shared__ int T[16][NBLK_E + 4];
    const int t = threadIdx.x;
    const int w = t >> 6;
    const int l = t & 63;
    const size_t base = (size_t)blockIdx.x * NBLK_E * 16;

    for (int i = t; i < NBLK_E * 16; i += 256) {
        int k = i >> 4, bl = i & 15;
        T[bl][k] = c2d[base + i];
    }
    __syncthreads();

#pragma unroll
    for (int q = 0; q < 4; ++q) {
        const int bl = w * 4 + q;
        int loc[CPL];
        int sum = 0;
#pragma unroll
        for (int j = 0; j < CPL; ++j) {
            int v = T[bl][l * CPL + j];
            loc[j] = sum;
            sum += v;
        }
        int s = sum;
#pragma unroll
        for (int off = 1; off < 64; off <<= 1) {
            int u = __shfl_up(s, off);
            if (l >= off) s += u;
        }
        if (l == 63) bsum[blockIdx.x * 16 + bl] = s;   // bucket total
        int ex = s - sum;
#pragma unroll
        for (int j = 0; j < CPL; ++j)
            T[bl][l * CPL + j] = ex + loc[j];
    }
    __syncthreads();

    for (int i = t; i < NBLK_E * 16; i += 256) {
        int k = i >> 4, bl = i & 15;
        c2d[base + i] = T[bl][k];
    }
}

// ---------------------------------------------------------------------------
// Scatter: per-block replicated bucket-base scan (kills scan_buckets
// dispatch; validated R13/R14). Block 0 persists bbase for sort_gather.
// Record: x = col(17b) | (row&31)<<17 ; y = val bits.
// ---------------------------------------------------------------------------
__global__ __launch_bounds__(256) void bucket_scatter3(const int* __restrict__ rows,
                                                       const int* __restrict__ cols,
                                                       const float* __restrict__ vals,
                                                       const int* __restrict__ c2d,
                                                       const int* __restrict__ bsum,
                                                       int* __restrict__ bbase,
                                                       uint2* __restrict__ etmp) {
    __shared__ int s[256];
    __shared__ int off[N_BUCKETS];
    const int t = threadIdx.x;
    const int blk = blockIdx.x;

    int loc[13];
    int sum = 0;
#pragma unroll
    for (int j = 0; j < 13; ++j) {
        int idx = t * 13 + j;
        int v = (idx < N_BUCKETS) ? bsum[idx] : 0;
        loc[j] = sum;
        sum += v;
    }
    s[t] = sum;
    __syncthreads();
#pragma unroll
    for (int o = 1; o < 256; o <<= 1) {
        int x = (t >= o) ? s[t - o] : 0;
        __syncthreads();
        s[t] += x;
        __syncthreads();
    }
    int base0 = s[t] - sum;
#pragma unroll
    for (int j = 0; j < 13; ++j) {
        int idx = t * 13 + j;
        if (idx < N_BUCKETS) {
            int bb = base0 + loc[j];
            off[idx] = bb + c2d[C2D_IDX(idx, blk)];
            if (blk == 0) bbase[idx] = bb;
        }
    }
    __syncthreads();

    const int base = blk * EPB;
    for (int i = t; i < EPB; i += 256) {
        int e = base + i;
        int r = rows[e];
        int b = r >> BUCKET_BITS;
        int pos = atomicAdd(&off[b], 1);
        etmp[pos] = make_uint2((unsigned)cols[e] |
                               ((unsigned)(r & (BUCKET_ROWS - 1)) << 17),
                               __float_as_uint(vals[e]));
    }
}

// ---------------------------------------------------------------------------
// Fused sort+gather (unchanged, validated R11-R14): one block per bucket.
// ---------------------------------------------------------------------------
__global__ __launch_bounds__(256) void sort_gather(const uint2* __restrict__ etmp,
                                                   const int* __restrict__ bbase,
                                                   const int* __restrict__ bsum,
                                                   const ushort* __restrict__ support,
                                                   uint2* __restrict__ edge_g,
                                                   float* __restrict__ out) {
    __shared__ uint2 eL[CAP];                // 12,288 B
    __shared__ int cnt[BUCKET_ROWS], pos[BUCKET_ROWS], fill[BUCKET_ROWS];
    const int t = threadIdx.x;
    const int lane = t & 63;
    const int w = t >> 6;
    const int b = blockIdx.x;
    const int r0 = b << BUCKET_BITS;
    const int s0 = bbase[b];
    const int n  = bsum[b];

    if (t < BUCKET_ROWS) cnt[t] = 0;
    __syncthreads();

    for (int i = t; i < n; i += 256)
        atomicAdd(&cnt[etmp[s0 + i].x >> 17], 1);
    __syncthreads();

    if (t < 64) {
        int v = (t < 32) ? cnt[t] : 0;
        int s = v;
#pragma unroll
        for (int off = 1; off < 32; off <<= 1) {
            int u = __shfl_up(s, off);
            if (lane >= off) s += u;
        }
        if (t < 32) { pos[t] = s - v; fill[t] = 0; }
    }
    __syncthreads();

    const bool inLDS = (n <= CAP);
    if (inLDS) {
        for (int i = t; i < n; i += 256) {
            uint2 u = etmp[s0 + i];
            int r = (int)(u.x >> 17);
            int p = pos[r] + atomicAdd(&fill[r], 1);
            eL[p] = make_uint2(u.x & 0x1FFFFu, u.y);
        }
    } else {
        for (int i = t; i < n; i += 256) {
            uint2 u = etmp[s0 + i];
            int r = (int)(u.x >> 17);
            int p = pos[r] + atomicAdd(&fill[r], 1);
            edge_g[s0 + p] = make_uint2(u.x & 0x1FFFFu, u.y);
        }
    }
    __syncthreads();

    const int h = lane >> 5;
    const int c = lane & 31;

#define GATHER_BODY(SRC)                                                          \
    for (int rr = w; rr < BUCKET_ROWS; rr += 4) {                                 \
        int e = pos[rr], end = pos[rr] + cnt[rr];                                 \
        float2 acc = {0.f, 0.f};                                                  \
        for (; e + 3 < end; e += 4) {                                             \
            uint2 p0 = SRC(e + h);                                                \
            uint2 p1 = SRC(e + 2 + h);                                            \
            unsigned s0v = *reinterpret_cast<const unsigned*>(                    \
                support + (size_t)p0.x * D_OUT + 2 * c);                          \
            unsigned s1v = *reinterpret_cast<const unsigned*>(                    \
                support + (size_t)p1.x * D_OUT + 2 * c);                          \
            float v0 = __uint_as_float(p0.y);                                     \
            float v1 = __uint_as_float(p1.y);                                     \
            acc.x = fmaf(v0, bf16_to_f32((ushort)(s0v & 0xFFFFu)), acc.x);        \
            acc.y = fmaf(v0, bf16_to_f32((ushort)(s0v >> 16)), acc.y);            \
            acc.x = fmaf(v1, bf16_to_f32((ushort)(s1v & 0xFFFFu)), acc.x);        \
            acc.y = fmaf(v1, bf16_to_f32((ushort)(s1v >> 16)), acc.y);            \
        }                                                                         \
        for (int ee = e + h; ee < end; ee += 2) {                                 \
            uint2 p = SRC(ee);                                                    \
            unsigned sv = *reinterpret_cast<const unsigned*>(                     \
                support + (size_t)p.x * D_OUT + 2 * c);                           \
            float v = __uint_as_float(p.y);                                       \
            acc.x = fmaf(v, bf16_to_f32((ushort)(sv & 0xFFFFu)), acc.x);          \
            acc.y = fmaf(v, bf16_to_f32((ushort)(sv >> 16)), acc.y);              \
        }                                                                         \
        acc.x += __shfl_xor(acc.x, 32);                                           \
        acc.y += __shfl_xor(acc.y, 32);                                           \
        if (h == 0)                                                               \
            *reinterpret_cast<float2*>(out + (size_t)(r0 + rr) * D_OUT + 2 * c) = acc; \
    }

    if (inLDS) {
#define SRCL(i) eL[i]
        GATHER_BODY(SRCL)
#undef SRCL
    } else {
        const uint2* eg = edge_g + s0;
#define SRCG(i) eg[i]
        GATHER_BODY(SRCG)
#undef SRCG
    }
#undef GATHER_BODY
}

// ---------------------------------------------------------------------------
// Fallback path (ws too small): wprep + gemm + zero + atomic scatter.
// ---------------------------------------------------------------------------
__global__ __launch_bounds__(256) void wprep_standalone(const float* __restrict__ W,
                                                        ushort* __restrict__ Wbf) {
    wprep_body(blockIdx.x, threadIdx.x, W, Wbf);
}

__global__ void zero_out(float4* __restrict__ out, int n4) {
    int i = blockIdx.x * blockDim.x + threadIdx.x;
    int stride = gridDim.x * blockDim.x;
    for (; i < n4; i += stride) out[i] = float4{0.0f, 0.0f, 0.0f, 0.0f};
}

__global__ __launch_bounds__(256) void spmm_scatter(const int* __restrict__ rows,
                                                    const int* __restrict__ cols,
                                                    const float* __restrict__ vals,
                                                    const ushort* __restrict__ support,
                                                    float* __restrict__ out,
                                                    int n_edges) {
    const int lane = threadIdx.x & 63;
    const int wave_global = (int)((blockIdx.x * blockDim.x + threadIdx.x) >> 6);
    const int n_waves = (int)((gridDim.x * blockDim.x) >> 6);

    for (int base = wave_global * 64; base < n_edges; base += n_waves * 64) {
        int my_e = base + lane;
        int r = rows[my_e];
        int c = cols[my_e];
        float v = vals[my_e];

        int cnt = min(64, n_edges - base);
        for (int i = 0; i < cnt; ++i) {
            int row = __shfl(r, i);
            int col = __shfl(c, i);
            float val = __shfl(v, i);
            float s = bf16_to_f32(support[(size_t)col * D_OUT + lane]);
            atomicAdd(&out[(size_t)row * D_OUT + lane], val * s);
        }
    }
}

extern "C" void kernel_launch(void* const* d_in, const int* in_sizes, int n_in,
                              void* d_out, int out_size, void* d_ws, size_t ws_size,
                              hipStream_t stream) {
    const float* X      = (const float*)d_in[0];
    const float* W      = (const float*)d_in[1];
    const int*   A_rows = (const int*)d_in[2];
    const int*   A_cols = (const int*)d_in[3];
    const float* A_vals = (const float*)d_in[4];
    float* out = (float*)d_out;

    char* ws = (char*)d_ws;
    ushort* support = (ushort*)(ws + OFF_SUPPORT);
    ushort* Wbf     = (ushort*)(ws + OFF_WBF);

    const int gemm_blocks = (N_NODES + 127) / 128;  // 782

    if (ws_size >= (size_t)WS_NEEDED) {
        int*   bsum   = (int*)(ws + OFF_BSUM);
        int*   bbase  = (int*)(ws + OFF_BBASE);
        int*   c2d    = (int*)(ws + OFF_C2D);     // aliases edge_g region
        uint2* etmp   = (uint2*)(ws + OFF_ETMP);
        uint2* edge_g = (uint2*)(ws + OFF_EDGEG);

        // d1: per-chunk bucket histograms + W bf16 prep (8 rider blocks)
        bucket_count<<<NBLK_E + 8, 256, 0, stream>>>(A_rows, c2d, W, Wbf);
        // d2: per-bucket chunk-offset scan + bucket totals
        scan_groups<<<N_GROUPS, 256, 0, stream>>>(c2d, bsum);
        // d3: scatter (bucket bases computed in-block; block 0 persists bbase)
        bucket_scatter3<<<NBLK_E, 256, 0, stream>>>(A_rows, A_cols, A_vals,
                                                    c2d, bsum, bbase, etmp);
        // d4: support = bf16(X @ W)  (double-buffered X staging, global Wbf)
        gemm_xw_mfma<<<gemm_blocks, 256, 0, stream>>>(X, Wbf, support);
        // d5: fused per-bucket row-sort + gather
        sort_gather<<<N_BUCKETS, 256, 0, stream>>>(etmp, bbase, bsum,
                                                   support, edge_g, out);
    } else {
        wprep_standalone<<<8, 256, 0, stream>>>(W, Wbf);
        int n4 = (N_NODES * D_OUT) / 4;
        zero_out<<<2048, 256, 0, stream>>>((float4*)out, n4);
        gemm_xw_mfma<<<gemm_blocks, 256, 0, stream>>>(X, Wbf, support);
        int chunks = N_EDGES / 64;
        spmm_scatter<<<(chunks + 3) / 4, 256, 0, stream>>>(A_rows, A_cols, A_vals,
                                                           support, out, N_EDGES);
    }
}

// Round 17
// 99.109 us; speedup vs baseline: 1.3948x; 1.1238x over previous
//
#include <hip/hip_runtime.h>

#define N_NODES 100000
#define N_EDGES 1200000
#define D_IN 256
#define D_OUT 64

#define BUCKET_BITS 5
#define BUCKET_ROWS 32
#define N_BUCKETS   (N_NODES / BUCKET_ROWS)      // 3125 exact
#define NBLK_E      640
#define EPB         (N_EDGES / NBLK_E)           // 1875 exact
#define N_GROUPS    196                           // ceil(3125/16)
#define CPL         10                            // chunks per lane (640/64)
#define CAP         1536                          // LDS edge staging per bucket

// c2d[group][chunk][16] : one 64B line per (group,chunk). 196*640*16*4 = 8,028,160 B.
#define C2D_IDX(b, k) ((((size_t)((b) >> 4) * NBLK_E + (k)) << 4) | ((b) & 15))

// ---- workspace layout (bytes) ----------------------------------------------
#define OFF_SUPPORT   0u            // bf16 support: 12,800,000
#define OFF_BSUM      12800000u     // 12,544
#define OFF_BBASE     12812544u     // 12,544
#define OFF_ETMP      12825088u     // 1.2M*8 = 9,600,000
#define OFF_EDGEG     22425088u     // 9,600,000 (c2d alias: 8,028,160)
#define OFF_C2D       OFF_EDGEG
#define WS_NEEDED     32025088u

using bf16x8 = __attribute__((ext_vector_type(8))) short;
using f32x4  = __attribute__((ext_vector_type(4))) float;

static __device__ __forceinline__ ushort f32_to_bf16_rne(float f) {
    unsigned bits = __float_as_uint(f);
    unsigned r = (bits + 0x7FFFu + ((bits >> 16) & 1u)) >> 16;
    return (ushort)r;
}
static __device__ __forceinline__ float bf16_to_f32(ushort u) {
    return __uint_as_float((unsigned)u << 16);
}
static __device__ __forceinline__ unsigned pack2bf(float a, float b) {
    return (unsigned)f32_to_bf16_rne(a) | ((unsigned)f32_to_bf16_rne(b) << 16);
}

// ---------------------------------------------------------------------------
// support(bf16) = X @ W — EXACT R4/R11 structure (the empirically fastest):
// 782 blocks, 128-row tile, Xs + WtT in LDS (40 KB, 4 blocks/CU), 2 barriers
// per k-step, X prefetch between them. ONLY change vs R4: W staging uses the
// R15-validated conflict-free pattern (lane=column, pack2bf -> uint4 store,
// 8 lanes/bank-quad = the 8-sweep minimum; measured 0 conflicts).
// ---------------------------------------------------------------------------
__global__ __launch_bounds__(256, 4) void gemm_xw_mfma(const float* __restrict__ X,
                                                       const float* __restrict__ W,
                                                       ushort* __restrict__ support) {
    __shared__ ushort XsT[4][128][8];   // 8 KB
    __shared__ ushort WtT[32][64][8];   // 32 KB

    const int t = threadIdx.x;
    const int row0 = blockIdx.x * 128;
    const int lane = t & 63;
    const int w = t >> 6;
    const int lr = lane & 15;
    const int lg = lane >> 4;

    // ---- stage W once, conflict-free (R15-validated) ----
    {
        const int c   = t & 63;     // column = lane -> coalesced global reads
        const int kg0 = t >> 6;     // 0..3
#pragma unroll
        for (int i = 0; i < 8; ++i) {
            int kg = kg0 + i * 4;   // 0..31
            uint4 u;
            u.x = pack2bf(W[(size_t)(kg * 8 + 0) * D_OUT + c],
                          W[(size_t)(kg * 8 + 1) * D_OUT + c]);
            u.y = pack2bf(W[(size_t)(kg * 8 + 2) * D_OUT + c],
                          W[(size_t)(kg * 8 + 3) * D_OUT + c]);
            u.z = pack2bf(W[(size_t)(kg * 8 + 4) * D_OUT + c],
                          W[(size_t)(kg * 8 + 5) * D_OUT + c]);
            u.w = pack2bf(W[(size_t)(kg * 8 + 6) * D_OUT + c],
                          W[(size_t)(kg * 8 + 7) * D_OUT + c]);
            *reinterpret_cast<uint4*>(&WtT[kg][c][0]) = u;
        }
    }

    int  xrow[4], xq[4];
    bool xval[4];
#pragma unroll
    for (int p = 0; p < 4; ++p) {
        int idx = t + p * 256;
        xrow[p] = idx >> 3;
        xq[p]   = idx & 7;
        xval[p] = (row0 + xrow[p]) < N_NODES;
    }

    float4 xreg[4];
#pragma unroll
    for (int p = 0; p < 4; ++p) {
        xreg[p] = make_float4(0.f, 0.f, 0.f, 0.f);
        if (xval[p])
            xreg[p] = *reinterpret_cast<const float4*>(
                X + (size_t)(row0 + xrow[p]) * D_IN + xq[p] * 4);
    }

    f32x4 acc[2][4];
#pragma unroll
    for (int mi = 0; mi < 2; ++mi)
#pragma unroll
        for (int ni = 0; ni < 4; ++ni) acc[mi][ni] = (f32x4){0.f, 0.f, 0.f, 0.f};

    for (int kt = 0; kt < 8; ++kt) {
#pragma unroll
        for (int p = 0; p < 4; ++p) {
            uint2 u;
            u.x = pack2bf(xreg[p].x, xreg[p].y);
            u.y = pack2bf(xreg[p].z, xreg[p].w);
            *reinterpret_cast<uint2*>(&XsT[xq[p] >> 1][xrow[p]][(xq[p] & 1) * 4]) = u;
        }
        __syncthreads();

        if (kt < 7) {
#pragma unroll
            for (int p = 0; p < 4; ++p) {
                if (xval[p])
                    xreg[p] = *reinterpret_cast<const float4*>(
                        X + (size_t)(row0 + xrow[p]) * D_IN + (kt + 1) * 32 + xq[p] * 4);
            }
        }

        bf16x8 a0 = *reinterpret_cast<const bf16x8*>(&XsT[lg][w * 32 + lr][0]);
        bf16x8 a1 = *reinterpret_cast<const bf16x8*>(&XsT[lg][w * 32 + 16 + lr][0]);
#pragma unroll
        for (int ni = 0; ni < 4; ++ni) {
            bf16x8 b = *reinterpret_cast<const bf16x8*>(&WtT[kt * 4 + lg][ni * 16 + lr][0]);
            acc[0][ni] = __builtin_amdgcn_mfma_f32_16x16x32_bf16(a0, b, acc[0][ni], 0, 0, 0);
            acc[1][ni] = __builtin_amdgcn_mfma_f32_16x16x32_bf16(a1, b, acc[1][ni], 0, 0, 0);
        }
        __syncthreads();
    }

    // ---- C write: D row = lg*4+reg, col = lr (m89-verified) ----
#pragma unroll
    for (int mi = 0; mi < 2; ++mi) {
#pragma unroll
        for (int reg = 0; reg < 4; ++reg) {
            int grow = row0 + w * 32 + mi * 16 + lg * 4 + reg;
            if (grow < N_NODES) {
#pragma unroll
                for (int ni = 0; ni < 4; ++ni)
                    support[(size_t)grow * D_OUT + ni * 16 + lr] =
                        f32_to_bf16_rne(acc[mi][ni][reg]);
            }
        }
    }
}

// ---------------------------------------------------------------------------
// Per-chunk bucket histogram (LDS-private) -> line-granular c2d.
// ---------------------------------------------------------------------------
__global__ __launch_bounds__(256) void bucket_count(const int* __restrict__ rows,
                                                    int* __restrict__ c2d) {
    __shared__ int h[N_BUCKETS];
    for (int i = threadIdx.x; i < N_BUCKETS; i += 256) h[i] = 0;
    __syncthreads();
    const int base = blockIdx.x * EPB;
    for (int i = threadIdx.x; i < EPB; i += 256)
        atomicAdd(&h[rows[base + i] >> BUCKET_BITS], 1);
    __syncthreads();
    const int k = blockIdx.x;
    for (int b = threadIdx.x; b < N_GROUPS * 16; b += 256)
        c2d[C2D_IDX(b, k)] = (b < N_BUCKETS) ? h[b] : 0;
}

// ---------------------------------------------------------------------------
// Per-bucket exclusive scan over 640 chunk counts (grouped/coalesced layout);
// emits per-bucket totals bsum[b]. (Validated R10-R15.)
// ---------------------------------------------------------------------------
__global__ __launch_bounds__(256) void scan_groups(int* __restrict__ c2d,
                                                   int* __restrict__ bsum) {
    __shared__ int T[16][NBLK_E + 4];
    const int t = threadIdx.x;
    const int w = t >> 6;
    const int l = t & 63;
    const size_t base = (size_t)blockIdx.x * NBLK_E * 16;

    for (int i = t; i < NBLK_E * 16; i += 256) {
        int k = i >> 4, bl = i & 15;
        T[bl][k] = c2d[base + i];
    }
    __syncthreads();

#pragma unroll
    for (int q = 0; q < 4; ++q) {
        const int bl = w * 4 + q;
        int loc[CPL];
        int sum = 0;
#pragma unroll
        for (int j = 0; j < CPL; ++j) {
            int v = T[bl][l * CPL + j];
            loc[j] = sum;
            sum += v;
        }
        int s = sum;
#pragma unroll
        for (int off = 1; off < 64; off <<= 1) {
            int u = __shfl_up(s, off);
            if (l >= off) s += u;
        }
        if (l == 63) bsum[blockIdx.x * 16 + bl] = s;   // bucket total
        int ex = s - sum;
#pragma unroll
        for (int j = 0; j < CPL; ++j)
            T[bl][l * CPL + j] = ex + loc[j];
    }
    __syncthreads();

    for (int i = t; i < NBLK_E * 16; i += 256) {
        int k = i >> 4, bl = i & 15;
        c2d[base + i] = T[bl][k];
    }
}

// ---------------------------------------------------------------------------
// Scatter: per-block replicated bucket-base scan (kills scan_buckets
// dispatch; validated R13-R15). Block 0 persists bbase for sort_gather.
// Record: x = col(17b) | (row&31)<<17 ; y = val bits.
// ---------------------------------------------------------------------------
__global__ __launch_bounds__(256) void bucket_scatter3(const int* __restrict__ rows,
                                                       const int* __restrict__ cols,
                                                       const float* __restrict__ vals,
                                                       const int* __restrict__ c2d,
                                                       const int* __restrict__ bsum,
                                                       int* __restrict__ bbase,
                                                       uint2* __restrict__ etmp) {
    __shared__ int s[256];
    __shared__ int off[N_BUCKETS];
    const int t = threadIdx.x;
    const int blk = blockIdx.x;

    int loc[13];
    int sum = 0;
#pragma unroll
    for (int j = 0; j < 13; ++j) {
        int idx = t * 13 + j;
        int v = (idx < N_BUCKETS) ? bsum[idx] : 0;
        loc[j] = sum;
        sum += v;
    }
    s[t] = sum;
    __syncthreads();
#pragma unroll
    for (int o = 1; o < 256; o <<= 1) {
        int x = (t >= o) ? s[t - o] : 0;
        __syncthreads();
        s[t] += x;
        __syncthreads();
    }
    int base0 = s[t] - sum;
#pragma unroll
    for (int j = 0; j < 13; ++j) {
        int idx = t * 13 + j;
        if (idx < N_BUCKETS) {
            int bb = base0 + loc[j];
            off[idx] = bb + c2d[C2D_IDX(idx, blk)];
            if (blk == 0) bbase[idx] = bb;
        }
    }
    __syncthreads();

    const int base = blk * EPB;
    for (int i = t; i < EPB; i += 256) {
        int e = base + i;
        int r = rows[e];
        int b = r >> BUCKET_BITS;
        int pos = atomicAdd(&off[b], 1);
        etmp[pos] = make_uint2((unsigned)cols[e] |
                               ((unsigned)(r & (BUCKET_ROWS - 1)) << 17),
                               __float_as_uint(vals[e]));
    }
}

// ---------------------------------------------------------------------------
// Fused sort+gather (unchanged, validated R11-R15): one block per bucket.
// ---------------------------------------------------------------------------
__global__ __launch_bounds__(256) void sort_gather(const uint2* __restrict__ etmp,
                                                   const int* __restrict__ bbase,
                                                   const int* __restrict__ bsum,
                                                   const ushort* __restrict__ support,
                                                   uint2* __restrict__ edge_g,
                                                   float* __restrict__ out) {
    __shared__ uint2 eL[CAP];                // 12,288 B
    __shared__ int cnt[BUCKET_ROWS], pos[BUCKET_ROWS], fill[BUCKET_ROWS];
    const int t = threadIdx.x;
    const int lane = t & 63;
    const int w = t >> 6;
    const int b = blockIdx.x;
    const int r0 = b << BUCKET_BITS;
    const int s0 = bbase[b];
    const int n  = bsum[b];

    if (t < BUCKET_ROWS) cnt[t] = 0;
    __syncthreads();

    for (int i = t; i < n; i += 256)
        atomicAdd(&cnt[etmp[s0 + i].x >> 17], 1);
    __syncthreads();

    if (t < 64) {
        int v = (t < 32) ? cnt[t] : 0;
        int s = v;
#pragma unroll
        for (int off = 1; off < 32; off <<= 1) {
            int u = __shfl_up(s, off);
            if (lane >= off) s += u;
        }
        if (t < 32) { pos[t] = s - v; fill[t] = 0; }
    }
    __syncthreads();

    const bool inLDS = (n <= CAP);
    if (inLDS) {
        for (int i = t; i < n; i += 256) {
            uint2 u = etmp[s0 + i];
            int r = (int)(u.x >> 17);
            int p = pos[r] + atomicAdd(&fill[r], 1);
            eL[p] = make_uint2(u.x & 0x1FFFFu, u.y);
        }
    } else {
        for (int i = t; i < n; i += 256) {
            uint2 u = etmp[s0 + i];
            int r = (int)(u.x >> 17);
            int p = pos[r] + atomicAdd(&fill[r], 1);
            edge_g[s0 + p] = make_uint2(u.x & 0x1FFFFu, u.y);
        }
    }
    __syncthreads();

    const int h = lane >> 5;
    const int c = lane & 31;

#define GATHER_BODY(SRC)                                                          \
    for (int rr = w; rr < BUCKET_ROWS; rr += 4) {                                 \
        int e = pos[rr], end = pos[rr] + cnt[rr];                                 \
        float2 acc = {0.f, 0.f};                                                  \
        for (; e + 3 < end; e += 4) {                                             \
            uint2 p0 = SRC(e + h);                                                \
            uint2 p1 = SRC(e + 2 + h);                                            \
            unsigned s0v = *reinterpret_cast<const unsigned*>(                    \
                support + (size_t)p0.x * D_OUT + 2 * c);                          \
            unsigned s1v = *reinterpret_cast<const unsigned*>(                    \
                support + (size_t)p1.x * D_OUT + 2 * c);                          \
            float v0 = __uint_as_float(p0.y);                                     \
            float v1 = __uint_as_float(p1.y);                                     \
            acc.x = fmaf(v0, bf16_to_f32((ushort)(s0v & 0xFFFFu)), acc.x);        \
            acc.y = fmaf(v0, bf16_to_f32((ushort)(s0v >> 16)), acc.y);            \
            acc.x = fmaf(v1, bf16_to_f32((ushort)(s1v & 0xFFFFu)), acc.x);        \
            acc.y = fmaf(v1, bf16_to_f32((ushort)(s1v >> 16)), acc.y);            \
        }                                                                         \
        for (int ee = e + h; ee < end; ee += 2) {                                 \
            uint2 p = SRC(ee);                                                    \
            unsigned sv = *reinterpret_cast<const unsigned*>(                     \
                support + (size_t)p.x * D_OUT + 2 * c);                           \
            float v = __uint_as_float(p.y);                                       \
            acc.x = fmaf(v, bf16_to_f32((ushort)(sv & 0xFFFFu)), acc.x);          \
            acc.y = fmaf(v, bf16_to_f32((ushort)(sv >> 16)), acc.y);              \
        }                                                                         \
        acc.x += __shfl_xor(acc.x, 32);                                           \
        acc.y += __shfl_xor(acc.y, 32);                                           \
        if (h == 0)                                                               \
            *reinterpret_cast<float2*>(out + (size_t)(r0 + rr) * D_OUT + 2 * c) = acc; \
    }

    if (inLDS) {
#define SRCL(i) eL[i]
        GATHER_BODY(SRCL)
#undef SRCL
    } else {
        const uint2* eg = edge_g + s0;
#define SRCG(i) eg[i]
        GATHER_BODY(SRCG)
#undef SRCG
    }
#undef GATHER_BODY
}

// ---------------------------------------------------------------------------
// Fallback path (ws too small): zero + atomic scatter from bf16 support.
// ---------------------------------------------------------------------------
__global__ void zero_out(float4* __restrict__ out, int n4) {
    int i = blockIdx.x * blockDim.x + threadIdx.x;
    int stride = gridDim.x * blockDim.x;
    for (; i < n4; i += stride) out[i] = float4{0.0f, 0.0f, 0.0f, 0.0f};
}

__global__ __launch_bounds__(256) void spmm_scatter(const int* __restrict__ rows,
                                                    const int* __restrict__ cols,
                                                    const float* __restrict__ vals,
                                                    const ushort* __restrict__ support,
                                                    float* __restrict__ out,
                                                    int n_edges) {
    const int lane = threadIdx.x & 63;
    const int wave_global = (int)((blockIdx.x * blockDim.x + threadIdx.x) >> 6);
    const int n_waves = (int)((gridDim.x * blockDim.x) >> 6);

    for (int base = wave_global * 64; base < n_edges; base += n_waves * 64) {
        int my_e = base + lane;
        int r = rows[my_e];
        int c = cols[my_e];
        float v = vals[my_e];

        int cnt = min(64, n_edges - base);
        for (int i = 0; i < cnt; ++i) {
            int row = __shfl(r, i);
            int col = __shfl(c, i);
            float val = __shfl(v, i);
            float s = bf16_to_f32(support[(size_t)col * D_OUT + lane]);
            atomicAdd(&out[(size_t)row * D_OUT + lane], val * s);
        }
    }
}

extern "C" void kernel_launch(void* const* d_in, const int* in_sizes, int n_in,
                              void* d_out, int out_size, void* d_ws, size_t ws_size,
                              hipStream_t stream) {
    const float* X      = (const float*)d_in[0];
    const float* W      = (const float*)d_in[1];
    const int*   A_rows = (const int*)d_in[2];
    const int*   A_cols = (const int*)d_in[3];
    const float* A_vals = (const float*)d_in[4];
    float* out = (float*)d_out;

    char* ws = (char*)d_ws;
    ushort* support = (ushort*)(ws + OFF_SUPPORT);

    const int gemm_blocks = (N_NODES + 127) / 128;  // 782

    if (ws_size >= (size_t)WS_NEEDED) {
        int*   bsum   = (int*)(ws + OFF_BSUM);
        int*   bbase  = (int*)(ws + OFF_BBASE);
        int*   c2d    = (int*)(ws + OFF_C2D);     // aliases edge_g region
        uint2* etmp   = (uint2*)(ws + OFF_ETMP);
        uint2* edge_g = (uint2*)(ws + OFF_EDGEG);

        // d1: per-chunk bucket histograms
        bucket_count<<<NBLK_E, 256, 0, stream>>>(A_rows, c2d);
        // d2: per-bucket chunk-offset scan + bucket totals
        scan_groups<<<N_GROUPS, 256, 0, stream>>>(c2d, bsum);
        // d3: scatter (bucket bases computed in-block; block 0 persists bbase)
        bucket_scatter3<<<NBLK_E, 256, 0, stream>>>(A_rows, A_cols, A_vals,
                                                    c2d, bsum, bbase, etmp);
        // d4: support = bf16(X @ W)  (R4/R11 gemm + conflict-free W staging)
        gemm_xw_mfma<<<gemm_blocks, 256, 0, stream>>>(X, W, support);
        // d5: fused per-bucket row-sort + gather
        sort_gather<<<N_BUCKETS, 256, 0, stream>>>(etmp, bbase, bsum,
                                                   support, edge_g, out);
    } else {
        int n4 = (N_NODES * D_OUT) / 4;
        zero_out<<<2048, 256, 0, stream>>>((float4*)out, n4);
        gemm_xw_mfma<<<gemm_blocks, 256, 0, stream>>>(X, W, support);
        int chunks = N_EDGES / 64;
        spmm_scatter<<<(chunks + 3) / 4, 256, 0, stream>>>(A_rows, A_cols, A_vals,
                                                           support, out, N_EDGES);
    }
}

// Round 19
// 98.599 us; speedup vs baseline: 1.4020x; 1.0052x over previous
//
#include <hip/hip_runtime.h>

#define N_NODES 100000
#define N_EDGES 1200000
#define D_IN 256
#define D_OUT 64

#define BUCKET_BITS 5
#define BUCKET_ROWS 32
#define N_BUCKETS   (N_NODES / BUCKET_ROWS)      // 3125 exact
#define NBLK_E      640
#define EPB         (N_EDGES / NBLK_E)           // 1875 exact
#define N_GROUPS    196                           // ceil(3125/16)
#define CPL         10                            // chunks per lane (640/64)
#define CAP         1536                          // LDS edge staging per bucket

// c2d[group][chunk][16] : one 64B line per (group,chunk). 196*640*16*4 = 8,028,160 B.
#define C2D_IDX(b, k) ((((size_t)((b) >> 4) * NBLK_E + (k)) << 4) | ((b) & 15))

// ---- workspace layout (bytes) ----------------------------------------------
#define OFF_SUPPORT   0u            // bf16 support: 12,800,000
#define OFF_BSUM      12800000u     // 12,544
#define OFF_BBASE     12812544u     // 12,544
#define OFF_ETMP      12825088u     // 1.2M*8 = 9,600,000
#define OFF_EDGEG     22425088u     // 9,600,000 (c2d alias: 8,028,160)
#define OFF_C2D       OFF_EDGEG
#define WS_NEEDED     32025088u

using bf16x8 = __attribute__((ext_vector_type(8))) short;
using f32x4  = __attribute__((ext_vector_type(4))) float;

static __device__ __forceinline__ ushort f32_to_bf16_rne(float f) {
    unsigned bits = __float_as_uint(f);
    unsigned r = (bits + 0x7FFFu + ((bits >> 16) & 1u)) >> 16;
    return (ushort)r;
}
static __device__ __forceinline__ float bf16_to_f32(ushort u) {
    return __uint_as_float((unsigned)u << 16);
}
static __device__ __forceinline__ unsigned pack2bf(float a, float b) {
    return (unsigned)f32_to_bf16_rne(a) | ((unsigned)f32_to_bf16_rne(b) << 16);
}

// ---------------------------------------------------------------------------
// support(bf16) = X @ W — R16 gemm (empirically fastest) + Xs XOR-swizzle.
// 782 blocks, 128-row tile, Xs + WtT in LDS (40 KB, 4 blocks/CU), 2 barriers
// per k-step, X prefetch between them. W staging conflict-free (R15/R16).
// NEW vs R16: Xs physical row = row ^ (kg<<1) on BOTH store and read sides —
// removes the remaining 1.2M staging bank conflicts.
// ---------------------------------------------------------------------------
__global__ __launch_bounds__(256, 4) void gemm_xw_mfma(const float* __restrict__ X,
                                                       const float* __restrict__ W,
                                                       ushort* __restrict__ support) {
    __shared__ ushort XsT[4][128][8];   // 8 KB
    __shared__ ushort WtT[32][64][8];   // 32 KB

    const int t = threadIdx.x;
    const int row0 = blockIdx.x * 128;
    const int lane = t & 63;
    const int w = t >> 6;
    const int lr = lane & 15;
    const int lg = lane >> 4;

    // ---- stage W once, conflict-free (R15/R16-validated) ----
    {
        const int c   = t & 63;     // column = lane -> coalesced global reads
        const int kg0 = t >> 6;     // 0..3
#pragma unroll
        for (int i = 0; i < 8; ++i) {
            int kg = kg0 + i * 4;   // 0..31
            uint4 u;
            u.x = pack2bf(W[(size_t)(kg * 8 + 0) * D_OUT + c],
                          W[(size_t)(kg * 8 + 1) * D_OUT + c]);
            u.y = pack2bf(W[(size_t)(kg * 8 + 2) * D_OUT + c],
                          W[(size_t)(kg * 8 + 3) * D_OUT + c]);
            u.z = pack2bf(W[(size_t)(kg * 8 + 4) * D_OUT + c],
                          W[(size_t)(kg * 8 + 5) * D_OUT + c]);
            u.w = pack2bf(W[(size_t)(kg * 8 + 6) * D_OUT + c],
                          W[(size_t)(kg * 8 + 7) * D_OUT + c]);
            *reinterpret_cast<uint4*>(&WtT[kg][c][0]) = u;
        }
    }

    int  xrow[4], xq[4];
    bool xval[4];
#pragma unroll
    for (int p = 0; p < 4; ++p) {
        int idx = t + p * 256;
        xrow[p] = idx >> 3;
        xq[p]   = idx & 7;
        xval[p] = (row0 + xrow[p]) < N_NODES;
    }

    float4 xreg[4];
#pragma unroll
    for (int p = 0; p < 4; ++p) {
        xreg[p] = make_float4(0.f, 0.f, 0.f, 0.f);
        if (xval[p])
            xreg[p] = *reinterpret_cast<const float4*>(
                X + (size_t)(row0 + xrow[p]) * D_IN + xq[p] * 4);
    }

    f32x4 acc[2][4];
#pragma unroll
    for (int mi = 0; mi < 2; ++mi)
#pragma unroll
        for (int ni = 0; ni < 4; ++ni) acc[mi][ni] = (f32x4){0.f, 0.f, 0.f, 0.f};

    for (int kt = 0; kt < 8; ++kt) {
        // Xs staging, XOR-row-swizzled (store side)
#pragma unroll
        for (int p = 0; p < 4; ++p) {
            int kg = xq[p] >> 1;
            uint2 u;
            u.x = pack2bf(xreg[p].x, xreg[p].y);
            u.y = pack2bf(xreg[p].z, xreg[p].w);
            *reinterpret_cast<uint2*>(&XsT[kg][xrow[p] ^ (kg << 1)][(xq[p] & 1) * 4]) = u;
        }
        __syncthreads();

        if (kt < 7) {
#pragma unroll
            for (int p = 0; p < 4; ++p) {
                if (xval[p])
                    xreg[p] = *reinterpret_cast<const float4*>(
                        X + (size_t)(row0 + xrow[p]) * D_IN + (kt + 1) * 32 + xq[p] * 4);
            }
        }

        // fragment reads, same XOR (read side)
        bf16x8 a0 = *reinterpret_cast<const bf16x8*>(&XsT[lg][(w * 32 + lr) ^ (lg << 1)][0]);
        bf16x8 a1 = *reinterpret_cast<const bf16x8*>(&XsT[lg][(w * 32 + 16 + lr) ^ (lg << 1)][0]);
#pragma unroll
        for (int ni = 0; ni < 4; ++ni) {
            bf16x8 b = *reinterpret_cast<const bf16x8*>(&WtT[kt * 4 + lg][ni * 16 + lr][0]);
            acc[0][ni] = __builtin_amdgcn_mfma_f32_16x16x32_bf16(a0, b, acc[0][ni], 0, 0, 0);
            acc[1][ni] = __builtin_amdgcn_mfma_f32_16x16x32_bf16(a1, b, acc[1][ni], 0, 0, 0);
        }
        __syncthreads();
    }

    // ---- C write: D row = lg*4+reg, col = lr (m89-verified) ----
#pragma unroll
    for (int mi = 0; mi < 2; ++mi) {
#pragma unroll
        for (int reg = 0; reg < 4; ++reg) {
            int grow = row0 + w * 32 + mi * 16 + lg * 4 + reg;
            if (grow < N_NODES) {
#pragma unroll
                for (int ni = 0; ni < 4; ++ni)
                    support[(size_t)grow * D_OUT + ni * 16 + lr] =
                        f32_to_bf16_rne(acc[mi][ni][reg]);
            }
        }
    }
}

// ---------------------------------------------------------------------------
// Per-chunk bucket histogram (LDS-private) -> line-granular c2d.
// ---------------------------------------------------------------------------
__global__ __launch_bounds__(256) void bucket_count(const int* __restrict__ rows,
                                                    int* __restrict__ c2d) {
    __shared__ int h[N_BUCKETS];
    for (int i = threadIdx.x; i < N_BUCKETS; i += 256) h[i] = 0;
    __syncthreads();
    const int base = blockIdx.x * EPB;
    for (int i = threadIdx.x; i < EPB; i += 256)
        atomicAdd(&h[rows[base + i] >> BUCKET_BITS], 1);
    __syncthreads();
    const int k = blockIdx.x;
    for (int b = threadIdx.x; b < N_GROUPS * 16; b += 256)
        c2d[C2D_IDX(b, k)] = (b < N_BUCKETS) ? h[b] : 0;
}

// ---------------------------------------------------------------------------
// Per-bucket exclusive scan over 640 chunk counts (grouped/coalesced layout);
// emits per-bucket totals bsum[b]. (Validated R10-R16.)
// ---------------------------------------------------------------------------
__global__ __launch_bounds__(256) void scan_groups(int* __restrict__ c2d,
                                                   int* __restrict__ bsum) {
    __shared__ int T[16][NBLK_E + 4];
    const int t = threadIdx.x;
    const int w = t >> 6;
    const int l = t & 63;
    const size_t base = (size_t)blockIdx.x * NBLK_E * 16;

    for (int i = t; i < NBLK_E * 16; i += 256) {
        int k = i >> 4, bl = i & 15;
        T[bl][k] = c2d[base + i];
    }
    __syncthreads();

#pragma unroll
    for (int q = 0; q < 4; ++q) {
        const int bl = w * 4 + q;
        int loc[CPL];
        int sum = 0;
#pragma unroll
        for (int j = 0; j < CPL; ++j) {
            int v = T[bl][l * CPL + j];
            loc[j] = sum;
            sum += v;
        }
        int s = sum;
#pragma unroll
        for (int off = 1; off < 64; off <<= 1) {
            int u = __shfl_up(s, off);
            if (l >= off) s += u;
        }
        if (l == 63) bsum[blockIdx.x * 16 + bl] = s;   // bucket total
        int ex = s - sum;
#pragma unroll
        for (int j = 0; j < CPL; ++j)
            T[bl][l * CPL + j] = ex + loc[j];
    }
    __syncthreads();

    for (int i = t; i < NBLK_E * 16; i += 256) {
        int k = i >> 4, bl = i & 15;
        c2d[base + i] = T[bl][k];
    }
}

// ---------------------------------------------------------------------------
// Scatter: per-block replicated bucket-base scan (validated R13-R16).
// Block 0 persists bbase for sort_gather.
// Record: x = col(17b) | (row&31)<<17 ; y = val bits.
// ---------------------------------------------------------------------------
__global__ __launch_bounds__(256) void bucket_scatter3(const int* __restrict__ rows,
                                                       const int* __restrict__ cols,
                                                       const float* __restrict__ vals,
                                                       const int* __restrict__ c2d,
                                                       const int* __restrict__ bsum,
                                                       int* __restrict__ bbase,
                                                       uint2* __restrict__ etmp) {
    __shared__ int s[256];
    __shared__ int off[N_BUCKETS];
    const int t = threadIdx.x;
    const int blk = blockIdx.x;

    int loc[13];
    int sum = 0;
#pragma unroll
    for (int j = 0; j < 13; ++j) {
        int idx = t * 13 + j;
        int v = (idx < N_BUCKETS) ? bsum[idx] : 0;
        loc[j] = sum;
        sum += v;
    }
    s[t] = sum;
    __syncthreads();
#pragma unroll
    for (int o = 1; o < 256; o <<= 1) {
        int x = (t >= o) ? s[t - o] : 0;
        __syncthreads();
        s[t] += x;
        __syncthreads();
    }
    int base0 = s[t] - sum;
#pragma unroll
    for (int j = 0; j < 13; ++j) {
        int idx = t * 13 + j;
        if (idx < N_BUCKETS) {
            int bb = base0 + loc[j];
            off[idx] = bb + c2d[C2D_IDX(idx, blk)];
            if (blk == 0) bbase[idx] = bb;
        }
    }
    __syncthreads();

    const int base = blk * EPB;
    for (int i = t; i < EPB; i += 256) {
        int e = base + i;
        int r = rows[e];
        int b = r >> BUCKET_BITS;
        int pos = atomicAdd(&off[b], 1);
        etmp[pos] = make_uint2((unsigned)cols[e] |
                               ((unsigned)(r & (BUCKET_ROWS - 1)) << 17),
                               __float_as_uint(vals[e]));
    }
}

// ---------------------------------------------------------------------------
// Fused sort+gather (unchanged, validated R11-R16): one block per bucket.
// ---------------------------------------------------------------------------
__global__ __launch_bounds__(256) void sort_gather(const uint2* __restrict__ etmp,
                                                   const int* __restrict__ bbase,
                                                   const int* __restrict__ bsum,
                                                   const ushort* __restrict__ support,
                                                   uint2* __restrict__ edge_g,
                                                   float* __restrict__ out) {
    __shared__ uint2 eL[CAP];                // 12,288 B
    __shared__ int cnt[BUCKET_ROWS], pos[BUCKET_ROWS], fill[BUCKET_ROWS];
    const int t = threadIdx.x;
    const int lane = t & 63;
    const int w = t >> 6;
    const int b = blockIdx.x;
    const int r0 = b << BUCKET_BITS;
    const int s0 = bbase[b];
    const int n  = bsum[b];

    if (t < BUCKET_ROWS) cnt[t] = 0;
    __syncthreads();

    for (int i = t; i < n; i += 256)
        atomicAdd(&cnt[etmp[s0 + i].x >> 17], 1);
    __syncthreads();

    if (t < 64) {
        int v = (t < 32) ? cnt[t] : 0;
        int s = v;
#pragma unroll
        for (int off = 1; off < 32; off <<= 1) {
            int u = __shfl_up(s, off);
            if (lane >= off) s += u;
        }
        if (t < 32) { pos[t] = s - v; fill[t] = 0; }
    }
    __syncthreads();

    const bool inLDS = (n <= CAP);
    if (inLDS) {
        for (int i = t; i < n; i += 256) {
            uint2 u = etmp[s0 + i];
            int r = (int)(u.x >> 17);
            int p = pos[r] + atomicAdd(&fill[r], 1);
            eL[p] = make_uint2(u.x & 0x1FFFFu, u.y);
        }
    } else {
        for (int i = t; i < n; i += 256) {
            uint2 u = etmp[s0 + i];
            int r = (int)(u.x >> 17);
            int p = pos[r] + atomicAdd(&fill[r], 1);
            edge_g[s0 + p] = make_uint2(u.x & 0x1FFFFu, u.y);
        }
    }
    __syncthreads();

    const int h = lane >> 5;
    const int c = lane & 31;

#define GATHER_BODY(SRC)                                                          \
    for (int rr = w; rr < BUCKET_ROWS; rr += 4) {                                 \
        int e = pos[rr], end = pos[rr] + cnt[rr];                                 \
        float2 acc = {0.f, 0.f};                                                  \
        for (; e + 3 < end; e += 4) {                                             \
            uint2 p0 = SRC(e + h);                                                \
            uint2 p1 = SRC(e + 2 + h);                                            \
            unsigned s0v = *reinterpret_cast<const unsigned*>(                    \
                support + (size_t)p0.x * D_OUT + 2 * c);                          \
            unsigned s1v = *reinterpret_cast<const unsigned*>(                    \
                support + (size_t)p1.x * D_OUT + 2 * c);                          \
            float v0 = __uint_as_float(p0.y);                                     \
            float v1 = __uint_as_float(p1.y);                                     \
            acc.x = fmaf(v0, bf16_to_f32((ushort)(s0v & 0xFFFFu)), acc.x);        \
            acc.y = fmaf(v0, bf16_to_f32((ushort)(s0v >> 16)), acc.y);            \
            acc.x = fmaf(v1, bf16_to_f32((ushort)(s1v & 0xFFFFu)), acc.x);        \
            acc.y = fmaf(v1, bf16_to_f32((ushort)(s1v >> 16)), acc.y);            \
        }                                                                         \
        for (int ee = e + h; ee < end; ee += 2) {                                 \
            uint2 p = SRC(ee);                                                    \
            unsigned sv = *reinterpret_cast<const unsigned*>(                     \
                support + (size_t)p.x * D_OUT + 2 * c);                           \
            float v = __uint_as_float(p.y);                                       \
            acc.x = fmaf(v, bf16_to_f32((ushort)(sv & 0xFFFFu)), acc.x);          \
            acc.y = fmaf(v, bf16_to_f32((ushort)(sv >> 16)), acc.y);              \
        }                                                                         \
        acc.x += __shfl_xor(acc.x, 32);                                           \
        acc.y += __shfl_xor(acc.y, 32);                                           \
        if (h == 0)                                                               \
            *reinterpret_cast<float2*>(out + (size_t)(r0 + rr) * D_OUT + 2 * c) = acc; \
    }

    if (inLDS) {
#define SRCL(i) eL[i]
        GATHER_BODY(SRCL)
#undef SRCL
    } else {
        const uint2* eg = edge_g + s0;
#define SRCG(i) eg[i]
        GATHER_BODY(SRCG)
#undef SRCG
    }
#undef GATHER_BODY
}

// ---------------------------------------------------------------------------
// Fallback path (ws too small): zero + atomic scatter from bf16 support.
// ---------------------------------------------------------------------------
__global__ void zero_out(float4* __restrict__ out, int n4) {
    int i = blockIdx.x * blockDim.x + threadIdx.x;
    int stride = gridDim.x * blockDim.x;
    for (; i < n4; i += stride) out[i] = float4{0.0f, 0.0f, 0.0f, 0.0f};
}

__global__ __launch_bounds__(256) void spmm_scatter(const int* __restrict__ rows,
                                                    const int* __restrict__ cols,
                                                    const float* __restrict__ vals,
                                                    const ushort* __restrict__ support,
                                                    float* __restrict__ out,
                                                    int n_edges) {
    const int lane = threadIdx.x & 63;
    const int wave_global = (int)((blockIdx.x * blockDim.x + threadIdx.x) >> 6);
    const int n_waves = (int)((gridDim.x * blockDim.x) >> 6);

    for (int base = wave_global * 64; base < n_edges; base += n_waves * 64) {
        int my_e = base + lane;
        int r = rows[my_e];
        int c = cols[my_e];
        float v = vals[my_e];

        int cnt = min(64, n_edges - base);
        for (int i = 0; i < cnt; ++i) {
            int row = __shfl(r, i);
            int col = __shfl(c, i);
            float val = __shfl(v, i);
            float s = bf16_to_f32(support[(size_t)col * D_OUT + lane]);
            atomicAdd(&out[(size_t)row * D_OUT + lane], val * s);
        }
    }
}

extern "C" void kernel_launch(void* const* d_in, const int* in_sizes, int n_in,
                              void* d_out, int out_size, void* d_ws, size_t ws_size,
                              hipStream_t stream) {
    const float* X      = (const float*)d_in[0];
    const float* W      = (const float*)d_in[1];
    const int*   A_rows = (const int*)d_in[2];
    const int*   A_cols = (const int*)d_in[3];
    const float* A_vals = (const float*)d_in[4];
    float* out = (float*)d_out;

    char* ws = (char*)d_ws;
    ushort* support = (ushort*)(ws + OFF_SUPPORT);

    const int gemm_blocks = (N_NODES + 127) / 128;  // 782

    if (ws_size >= (size_t)WS_NEEDED) {
        int*   bsum   = (int*)(ws + OFF_BSUM);
        int*   bbase  = (int*)(ws + OFF_BBASE);
        int*   c2d    = (int*)(ws + OFF_C2D);     // aliases edge_g region
        uint2* etmp   = (uint2*)(ws + OFF_ETMP);
        uint2* edge_g = (uint2*)(ws + OFF_EDGEG);

        // d1: per-chunk bucket histograms
        bucket_count<<<NBLK_E, 256, 0, stream>>>(A_rows, c2d);
        // d2: per-bucket chunk-offset scan + bucket totals
        scan_groups<<<N_GROUPS, 256, 0, stream>>>(c2d, bsum);
        // d3: scatter (bucket bases computed in-block; block 0 persists bbase)
        bucket_scatter3<<<NBLK_E, 256, 0, stream>>>(A_rows, A_cols, A_vals,
                                                    c2d, bsum, bbase, etmp);
        // d4: support = bf16(X @ W)  (R16 gemm + Xs XOR-swizzle)
        gemm_xw_mfma<<<gemm_blocks, 256, 0, stream>>>(X, W, support);
        // d5: fused per-bucket row-sort + gather
        sort_gather<<<N_BUCKETS, 256, 0, stream>>>(etmp, bbase, bsum,
                                                   support, edge_g, out);
    } else {
        int n4 = (N_NODES * D_OUT) / 4;
        zero_out<<<2048, 256, 0, stream>>>((float4*)out, n4);
        gemm_xw_mfma<<<gemm_blocks, 256, 0, stream>>>(X, W, support);
        int chunks = N_EDGES / 64;
        spmm_scatter<<<(chunks + 3) / 4, 256, 0, stream>>>(A_rows, A_cols, A_vals,
                                                           support, out, N_EDGES);
    }
}